// Round 2
// baseline (1135.249 us; speedup 1.0000x reference)
//
#include <hip/hip_runtime.h>

#define N_NODES   50000
#define N_EDGES   1600000
#define FDIM_IN   128
#define HDIM      160
#define N_GRAPHS  512
#define BN_EPS    1e-5f

// ---------------- edge sort (counting sort by dst) ----------------

__global__ __launch_bounds__(256) void hist_kernel(const int* __restrict__ dst,
                                                   int* __restrict__ cnt, int E) {
    int e = blockIdx.x * 256 + threadIdx.x;
    if (e < E) atomicAdd(&cnt[dst[e]], 1);
}

__global__ __launch_bounds__(256) void inv_kernel(const int* __restrict__ cnt,
                                                  float* __restrict__ inv, int n) {
    int i = blockIdx.x * 256 + threadIdx.x;
    if (i < n) inv[i] = rsqrtf((float)(cnt[i] + 1));   // +1 = self loop
}

__global__ __launch_bounds__(1024) void scan_kernel(const int* __restrict__ cnt,
                                                    int* __restrict__ row_off,
                                                    int* __restrict__ cursor, int n) {
    __shared__ int wavesums[16];
    int t = threadIdx.x;
    int chunk = (n + 1023) >> 10;
    int lo = t * chunk;
    int hi = min(lo + chunk, n);
    int s = 0;
    for (int i = lo; i < hi; ++i) s += cnt[i];
    int lane = t & 63, wid = t >> 6;
    int incl = s;
    #pragma unroll
    for (int off = 1; off < 64; off <<= 1) {
        int v = __shfl_up(incl, off);
        if (lane >= off) incl += v;
    }
    if (lane == 63) wavesums[wid] = incl;
    __syncthreads();
    if (t < 16) {
        int v = wavesums[t];
        int inc2 = v;
        #pragma unroll
        for (int off = 1; off < 16; off <<= 1) {
            int u = __shfl_up(inc2, off);
            if (t >= off) inc2 += u;
        }
        wavesums[t] = inc2 - v;   // exclusive wave offset
    }
    __syncthreads();
    int run = wavesums[wid] + (incl - s);   // exclusive prefix of this chunk
    for (int i = lo; i < hi; ++i) {
        int c = cnt[i];
        row_off[i] = run;
        cursor[i]  = run;
        run += c;
    }
    if (lo < n && hi == n) row_off[n] = run;
}

__global__ __launch_bounds__(256) void scatter_kernel(const int* __restrict__ src,
                                                      const int* __restrict__ dst,
                                                      int* __restrict__ cursor,
                                                      int* __restrict__ ssrc, int E) {
    int e = blockIdx.x * 256 + threadIdx.x;
    if (e < E) {
        int d = dst[e];
        int pos = atomicAdd(&cursor[d], 1);
        ssrc[pos] = src[e];
    }
}

// ---------------- BN fold ----------------

__global__ void prep_kernel(const float* __restrict__ b, const float* __restrict__ g,
                            const float* __restrict__ be, const float* __restrict__ m,
                            const float* __restrict__ v, float* __restrict__ sc,
                            float* __restrict__ sh) {
    int t = threadIdx.x;
    if (t < HDIM) {
        float s = g[t] * rsqrtf(v[t] + BN_EPS);
        sc[t] = s;
        sh[t] = (b[t] - m[t]) * s + be[t];
    }
}

// ---------------- pre-scale: out = x * inv[node]  (C channels, float4 lanes) ----------------

template <int C>
__global__ __launch_bounds__(256) void scale_kernel(const float* __restrict__ x,
                                                    const float* __restrict__ inv,
                                                    float* __restrict__ out, int n) {
    constexpr int C4 = C / 4;
    int i = blockIdx.x * 256 + threadIdx.x;      // float4 index
    if (i < n * C4) {
        int node = i / C4;
        float w = inv[node];
        float4 v = ((const float4*)x)[i];
        v.x *= w; v.y *= w; v.z *= w; v.w *= w;
        ((float4*)out)[i] = v;
    }
}

// ---------------- channel-sliced aggregation ----------------
// in_s is pre-scaled by inv[src]. out[i] = inv[i] * (sum_{s in nbr(i)} in_s[s] + in_s[i])
// Block: 64 nodes x 4 float4-quads (16 channels per slice). Grid.y = C/16 slices.
// Per-slice gather working set = n*16*4B = 3.2MB -> fits 4MB per-XCD L2.

#define EDGE_CAP 3072

template <int C>
__global__ __launch_bounds__(256) void agg_sliced_kernel(const float* __restrict__ in_s,
                                                         const float* __restrict__ inv,
                                                         const int* __restrict__ row_off,
                                                         const int* __restrict__ ssrc,
                                                         float* __restrict__ out, int n) {
    __shared__ int sEdge[EDGE_CAP];
    __shared__ int sOff[65];
    int tid = threadIdx.x;
    int node0 = blockIdx.x * 64;
    int col = blockIdx.y * 16 + (tid & 3) * 4;   // channel offset of this thread's float4

    if (tid <= 64) sOff[tid] = row_off[min(node0 + tid, n)];
    __syncthreads();
    int beg = sOff[0], end = sOff[64];
    int nStage = min(end - beg, EDGE_CAP);
    for (int j = tid; j < nStage; j += 256) sEdge[j] = ssrc[beg + j];
    __syncthreads();

    int nl = tid >> 2;
    int node = node0 + nl;
    if (node >= n) return;

    // self-loop term
    float4 acc = *(const float4*)(in_s + (size_t)node * C + col);

    int jb = sOff[nl] - beg, je = sOff[nl + 1] - beg;
    int j = jb;
    for (; j + 1 < je; j += 2) {
        int s0 = (j < EDGE_CAP) ? sEdge[j] : ssrc[beg + j];
        int s1 = (j + 1 < EDGE_CAP) ? sEdge[j + 1] : ssrc[beg + j + 1];
        float4 v0 = *(const float4*)(in_s + (size_t)s0 * C + col);
        float4 v1 = *(const float4*)(in_s + (size_t)s1 * C + col);
        acc.x += v0.x + v1.x; acc.y += v0.y + v1.y;
        acc.z += v0.z + v1.z; acc.w += v0.w + v1.w;
    }
    if (j < je) {
        int s0 = (j < EDGE_CAP) ? sEdge[j] : ssrc[beg + j];
        float4 v0 = *(const float4*)(in_s + (size_t)s0 * C + col);
        acc.x += v0.x; acc.y += v0.y; acc.z += v0.z; acc.w += v0.w;
    }
    float w = inv[node];
    acc.x *= w; acc.y *= w; acc.z *= w; acc.w *= w;
    *(float4*)(out + (size_t)node * C + col) = acc;
}

// ---------------- fp32 GEMM: C[n x 160] = relu((A[n x K] @ B[K x 160]) * sc + sh) [* inv] ----------------

template <int K, bool SCALE>
__global__ __launch_bounds__(256) void gemm_kernel(const float* __restrict__ A,
                                                   const float* __restrict__ B,
                                                   const float* __restrict__ sc,
                                                   const float* __restrict__ sh,
                                                   const float* __restrict__ inv,
                                                   float* __restrict__ Cout, int n) {
    __shared__ float As[16 * 68];     // [k][row], padded
    __shared__ float Bs[16 * 160];    // [k][col]
    int tid = threadIdx.x;
    int row0 = blockIdx.x * 64;
    int tx = tid & 15, ty = tid >> 4;
    int ar = tid >> 2, ak4 = tid & 3;

    float acc[4][10];
    #pragma unroll
    for (int j = 0; j < 4; ++j)
        #pragma unroll
        for (int i = 0; i < 10; ++i) acc[j][i] = 0.f;

    float scv[10], shv[10];
    #pragma unroll
    for (int i = 0; i < 10; ++i) { scv[i] = sc[tx + 16 * i]; shv[i] = sh[tx + 16 * i]; }

    bool arow_ok = (row0 + ar) < n;
    const float* Arow = A + (size_t)(row0 + ar) * K;

    for (int k0 = 0; k0 < K; k0 += 16) {
        __syncthreads();
        float4 a = make_float4(0.f, 0.f, 0.f, 0.f);
        if (arow_ok) a = *(const float4*)(Arow + k0 + ak4 * 4);
        As[(ak4 * 4 + 0) * 68 + ar] = a.x;
        As[(ak4 * 4 + 1) * 68 + ar] = a.y;
        As[(ak4 * 4 + 2) * 68 + ar] = a.z;
        As[(ak4 * 4 + 3) * 68 + ar] = a.w;
        #pragma unroll
        for (int i = 0; i < 10; ++i)
            Bs[tid + 256 * i] = B[k0 * 160 + tid + 256 * i];
        __syncthreads();
        #pragma unroll
        for (int k = 0; k < 16; ++k) {
            float4 av = *(const float4*)&As[k * 68 + ty * 4];
            float bv[10];
            #pragma unroll
            for (int i = 0; i < 10; ++i) bv[i] = Bs[k * 160 + tx + 16 * i];
            #pragma unroll
            for (int i = 0; i < 10; ++i) {
                acc[0][i] += av.x * bv[i];
                acc[1][i] += av.y * bv[i];
                acc[2][i] += av.z * bv[i];
                acc[3][i] += av.w * bv[i];
            }
        }
    }
    #pragma unroll
    for (int j = 0; j < 4; ++j) {
        int r = row0 + ty * 4 + j;
        if (r < n) {
            float wr = SCALE ? inv[r] : 1.0f;
            #pragma unroll
            for (int i = 0; i < 10; ++i) {
                float v = acc[j][i] * scv[i] + shv[i];
                Cout[(size_t)r * 160 + tx + 16 * i] = fmaxf(v, 0.f) * wr;
            }
        }
    }
}

// ---------------- mean pool (sorted batch) + MLP head ----------------

__global__ __launch_bounds__(256) void pool_head_kernel(const float* __restrict__ h,
                                                        const int* __restrict__ batch,
                                                        const float* __restrict__ Wc1,
                                                        const float* __restrict__ bc1,
                                                        const float* __restrict__ Wc2,
                                                        const float* __restrict__ bc2,
                                                        float* __restrict__ out, int n) {
    __shared__ float pooled[160];
    __shared__ float z[80];
    __shared__ int range[2];
    int g = blockIdx.x;
    int t = threadIdx.x;
    if (t < 2) {
        int target = g + t;
        int lo = 0, hi = n;
        while (lo < hi) {
            int mid = (lo + hi) >> 1;
            if (batch[mid] < target) lo = mid + 1; else hi = mid;
        }
        range[t] = lo;
    }
    __syncthreads();
    int lo = range[0], hi = range[1];
    if (t < 160) {
        float s = 0.f;
        for (int r = lo; r < hi; ++r) s += h[(size_t)r * 160 + t];
        pooled[t] = s / fmaxf((float)(hi - lo), 1.f);
    }
    __syncthreads();
    if (t < 80) {
        float s = bc1[t];
        for (int k = 0; k < 160; ++k) s += pooled[k] * Wc1[k * 80 + t];
        z[t] = fmaxf(s, 0.f);
    }
    __syncthreads();
    if (t < 2) {
        float s = bc2[t];
        for (int k = 0; k < 80; ++k) s += z[k] * Wc2[k * 2 + t];
        out[g * 2 + t] = s;
    }
}

// ---------------- launch ----------------

static inline size_t align256(size_t x) { return (x + 255) & ~(size_t)255; }

extern "C" void kernel_launch(void* const* d_in, const int* in_sizes, int n_in,
                              void* d_out, int out_size, void* d_ws, size_t ws_size,
                              hipStream_t stream) {
    const float* x   = (const float*)d_in[0];
    const int* ei    = (const int*)d_in[1];
    const int* batch = (const int*)d_in[2];
    const float* W1  = (const float*)d_in[3];
    const float* b1  = (const float*)d_in[4];
    const float* W2  = (const float*)d_in[5];
    const float* b2  = (const float*)d_in[6];
    const float* W3  = (const float*)d_in[7];
    const float* b3  = (const float*)d_in[8];
    const float* g1  = (const float*)d_in[9];
    const float* be1 = (const float*)d_in[10];
    const float* m1  = (const float*)d_in[11];
    const float* v1  = (const float*)d_in[12];
    const float* g2  = (const float*)d_in[13];
    const float* be2 = (const float*)d_in[14];
    const float* m2  = (const float*)d_in[15];
    const float* v2  = (const float*)d_in[16];
    const float* g3  = (const float*)d_in[17];
    const float* be3 = (const float*)d_in[18];
    const float* m3  = (const float*)d_in[19];
    const float* v3  = (const float*)d_in[20];
    const float* Wc1 = (const float*)d_in[21];
    const float* bc1 = (const float*)d_in[22];
    const float* Wc2 = (const float*)d_in[23];
    const float* bc2 = (const float*)d_in[24];
    float* out = (float*)d_out;

    const int N = in_sizes[2];          // 50000
    const int E = in_sizes[1] / 2;      // 1600000
    const int* src = ei;
    const int* dst = ei + E;

    char* w = (char*)d_ws;
    int*   cnt     = (int*)w;             w += align256((size_t)N * 4);
    int*   row_off = (int*)w;             w += align256((size_t)(N + 1) * 4);
    int*   cursor  = (int*)w;             w += align256((size_t)N * 4);
    float* inv     = (float*)w;           w += align256((size_t)N * 4);
    int*   ssrc    = (int*)w;             w += align256((size_t)E * 4);
    float* scsh    = (float*)w;           w += align256((size_t)6 * HDIM * 4);
    float* bufA    = (float*)w;           w += align256((size_t)N * HDIM * 4);
    float* bufB    = (float*)w;           w += align256((size_t)N * HDIM * 4);
    float* sc1 = scsh, *sh1 = scsh + 160, *sc2 = scsh + 320, *sh2 = scsh + 480,
         * sc3 = scsh + 640, *sh3 = scsh + 800;

    hipMemsetAsync(cnt, 0, (size_t)N * 4, stream);

    int gE = (E + 255) / 256;
    int gN = (N + 255) / 256;
    hist_kernel<<<gE, 256, 0, stream>>>(dst, cnt, E);
    inv_kernel<<<gN, 256, 0, stream>>>(cnt, inv, N);
    scan_kernel<<<1, 1024, 0, stream>>>(cnt, row_off, cursor, N);
    scatter_kernel<<<gE, 256, 0, stream>>>(src, dst, cursor, ssrc, E);

    prep_kernel<<<1, 256, 0, stream>>>(b1, g1, be1, m1, v1, sc1, sh1);
    prep_kernel<<<1, 256, 0, stream>>>(b2, g2, be2, m2, v2, sc2, sh2);
    prep_kernel<<<1, 256, 0, stream>>>(b3, g3, be3, m3, v3, sc3, sh3);

    int nodeBlocks = (N + 63) / 64;
    dim3 gAgg128(nodeBlocks, FDIM_IN / 16);
    dim3 gAgg160(nodeBlocks, HDIM / 16);
    int gGemm = nodeBlocks;

    // layer 1: xs = x*inv (into bufB), aggregate (sliced), GEMM(K=128)+BN+ReLU, out scaled by inv
    scale_kernel<128><<<(N * 32 + 255) / 256, 256, 0, stream>>>(x, inv, bufB, N);
    agg_sliced_kernel<128><<<gAgg128, 256, 0, stream>>>(bufB, inv, row_off, ssrc, bufA, N);
    gemm_kernel<128, true><<<gGemm, 256, 0, stream>>>(bufA, W1, sc1, sh1, inv, bufB, N);
    // layer 2
    agg_sliced_kernel<160><<<gAgg160, 256, 0, stream>>>(bufB, inv, row_off, ssrc, bufA, N);
    gemm_kernel<160, true><<<gGemm, 256, 0, stream>>>(bufA, W2, sc2, sh2, inv, bufB, N);
    // layer 3 (unscaled output -> h3)
    agg_sliced_kernel<160><<<gAgg160, 256, 0, stream>>>(bufB, inv, row_off, ssrc, bufA, N);
    gemm_kernel<160, false><<<gGemm, 256, 0, stream>>>(bufA, W3, sc3, sh3, inv, bufB, N);

    pool_head_kernel<<<N_GRAPHS, 256, 0, stream>>>(bufB, batch, Wc1, bc1, Wc2, bc2, out, N);
}

// Round 3
// 884.646 us; speedup vs baseline: 1.2833x; 1.2833x over previous
//
#include <hip/hip_runtime.h>

#define N_NODES   50000
#define N_EDGES   1600000
#define FDIM_IN   128
#define HDIM      160
#define N_GRAPHS  512
#define BN_EPS    1e-5f

// ---------------- bf16 helpers ----------------

__device__ __forceinline__ unsigned short f2bf(float f) {
    unsigned int u = __float_as_uint(f);
    return (unsigned short)((u + 0x7FFFu + ((u >> 16) & 1u)) >> 16);
}

__device__ __forceinline__ float4 bf4_to_f4(uint2 v) {
    float4 r;
    r.x = __uint_as_float(v.x << 16);
    r.y = __uint_as_float(v.x & 0xFFFF0000u);
    r.z = __uint_as_float(v.y << 16);
    r.w = __uint_as_float(v.y & 0xFFFF0000u);
    return r;
}

// ---------------- edge sort (counting sort by dst) ----------------

__global__ __launch_bounds__(256) void hist_kernel(const int* __restrict__ dst,
                                                   int* __restrict__ cnt, int E) {
    int e = blockIdx.x * 256 + threadIdx.x;
    if (e < E) atomicAdd(&cnt[dst[e]], 1);
}

__global__ __launch_bounds__(256) void inv_kernel(const int* __restrict__ cnt,
                                                  float* __restrict__ inv, int n) {
    int i = blockIdx.x * 256 + threadIdx.x;
    if (i < n) inv[i] = rsqrtf((float)(cnt[i] + 1));   // +1 = self loop
}

__global__ __launch_bounds__(1024) void scan_kernel(const int* __restrict__ cnt,
                                                    int* __restrict__ row_off,
                                                    int* __restrict__ cursor, int n) {
    __shared__ int wavesums[16];
    int t = threadIdx.x;
    int chunk = (n + 1023) >> 10;
    int lo = t * chunk;
    int hi = min(lo + chunk, n);
    int s = 0;
    for (int i = lo; i < hi; ++i) s += cnt[i];
    int lane = t & 63, wid = t >> 6;
    int incl = s;
    #pragma unroll
    for (int off = 1; off < 64; off <<= 1) {
        int v = __shfl_up(incl, off);
        if (lane >= off) incl += v;
    }
    if (lane == 63) wavesums[wid] = incl;
    __syncthreads();
    if (t < 16) {
        int v = wavesums[t];
        int inc2 = v;
        #pragma unroll
        for (int off = 1; off < 16; off <<= 1) {
            int u = __shfl_up(inc2, off);
            if (t >= off) inc2 += u;
        }
        wavesums[t] = inc2 - v;   // exclusive wave offset
    }
    __syncthreads();
    int run = wavesums[wid] + (incl - s);   // exclusive prefix of this chunk
    for (int i = lo; i < hi; ++i) {
        int c = cnt[i];
        row_off[i] = run;
        cursor[i]  = run;
        run += c;
    }
    if (lo < n && hi == n) row_off[n] = run;
}

__global__ __launch_bounds__(256) void scatter_kernel(const int* __restrict__ src,
                                                      const int* __restrict__ dst,
                                                      int* __restrict__ cursor,
                                                      int* __restrict__ ssrc, int E) {
    int e = blockIdx.x * 256 + threadIdx.x;
    if (e < E) {
        int d = dst[e];
        int pos = atomicAdd(&cursor[d], 1);
        ssrc[pos] = src[e];
    }
}

// ---------------- BN fold ----------------

__global__ void prep_kernel(const float* __restrict__ b, const float* __restrict__ g,
                            const float* __restrict__ be, const float* __restrict__ m,
                            const float* __restrict__ v, float* __restrict__ sc,
                            float* __restrict__ sh) {
    int t = threadIdx.x;
    if (t < HDIM) {
        float s = g[t] * rsqrtf(v[t] + BN_EPS);
        sc[t] = s;
        sh[t] = (b[t] - m[t]) * s + be[t];
    }
}

// ---------------- pre-scale + pack: out_bf16 = x * inv[node]  (C=128) ----------------

__global__ __launch_bounds__(256) void scale_bf16_kernel(const float* __restrict__ x,
                                                         const float* __restrict__ inv,
                                                         unsigned short* __restrict__ out,
                                                         int n) {
    int i = blockIdx.x * 256 + threadIdx.x;      // float4 index over n*32
    if (i < n * 32) {
        int node = i >> 5;
        float w = inv[node];
        float4 v = ((const float4*)x)[i];
        ushort4 o;
        o.x = f2bf(v.x * w); o.y = f2bf(v.y * w);
        o.z = f2bf(v.z * w); o.w = f2bf(v.w * w);
        ((ushort4*)out)[i] = o;
    }
}

// ---------------- aggregation over bf16 pre-scaled operand ----------------
// in_s[bf16] = h*inv (per-row). out[i] = inv[i] * (sum_{s in nbr(i)} in_s[s] + in_s[i])
// wave per node; lane owns 4 channels (8B loads). fp32 accumulate, fp32 out.

template <int C>
__global__ __launch_bounds__(256) void agg_bf16_kernel(const unsigned short* __restrict__ in_s,
                                                       const float* __restrict__ inv,
                                                       const int* __restrict__ row_off,
                                                       const int* __restrict__ ssrc,
                                                       float* __restrict__ out, int n) {
    constexpr int C4 = C / 4;
    int wave = threadIdx.x >> 6;
    int lane = threadIdx.x & 63;
    int node = blockIdx.x * 4 + wave;
    if (node >= n) return;
    int beg = row_off[node], end = row_off[node + 1];
    float inv_i = inv[node];
    const uint2* base = (const uint2*)in_s;      // row stride = C4 uint2s
    float4 acc = make_float4(0.f, 0.f, 0.f, 0.f);
    bool act = lane < C4;
    if (act) acc = bf4_to_f4(base[(size_t)node * C4 + lane]);   // self term
    int j = beg;
    for (; j + 3 < end; j += 4) {
        int s0 = ssrc[j], s1 = ssrc[j + 1], s2 = ssrc[j + 2], s3 = ssrc[j + 3];
        if (act) {
            uint2 r0 = base[(size_t)s0 * C4 + lane];
            uint2 r1 = base[(size_t)s1 * C4 + lane];
            uint2 r2 = base[(size_t)s2 * C4 + lane];
            uint2 r3 = base[(size_t)s3 * C4 + lane];
            float4 v0 = bf4_to_f4(r0), v1 = bf4_to_f4(r1);
            float4 v2 = bf4_to_f4(r2), v3 = bf4_to_f4(r3);
            acc.x += (v0.x + v1.x) + (v2.x + v3.x);
            acc.y += (v0.y + v1.y) + (v2.y + v3.y);
            acc.z += (v0.z + v1.z) + (v2.z + v3.z);
            acc.w += (v0.w + v1.w) + (v2.w + v3.w);
        }
    }
    for (; j < end; ++j) {
        int s0 = ssrc[j];
        if (act) {
            float4 v0 = bf4_to_f4(base[(size_t)s0 * C4 + lane]);
            acc.x += v0.x; acc.y += v0.y; acc.z += v0.z; acc.w += v0.w;
        }
    }
    if (act) {
        acc.x *= inv_i; acc.y *= inv_i; acc.z *= inv_i; acc.w *= inv_i;
        *(float4*)(out + (size_t)node * C + lane * 4) = acc;
    }
}

// ---------------- fp32 GEMM: relu((A[n x K] @ B[K x 160]) * sc + sh) ----------------
// OUTMODE 0: write fp32 (plain).  OUTMODE 1: write bf16, scaled by inv[row].

template <int K, int OUTMODE>
__global__ __launch_bounds__(256) void gemm_kernel(const float* __restrict__ A,
                                                   const float* __restrict__ B,
                                                   const float* __restrict__ sc,
                                                   const float* __restrict__ sh,
                                                   const float* __restrict__ inv,
                                                   float* __restrict__ CoutF,
                                                   unsigned short* __restrict__ CoutB,
                                                   int n) {
    __shared__ float As[16 * 68];     // [k][row], padded
    __shared__ float Bs[16 * 160];    // [k][col]
    int tid = threadIdx.x;
    int row0 = blockIdx.x * 64;
    int tx = tid & 15, ty = tid >> 4;
    int ar = tid >> 2, ak4 = tid & 3;

    float acc[4][10];
    #pragma unroll
    for (int j = 0; j < 4; ++j)
        #pragma unroll
        for (int i = 0; i < 10; ++i) acc[j][i] = 0.f;

    float scv[10], shv[10];
    #pragma unroll
    for (int i = 0; i < 10; ++i) { scv[i] = sc[tx + 16 * i]; shv[i] = sh[tx + 16 * i]; }

    bool arow_ok = (row0 + ar) < n;
    const float* Arow = A + (size_t)(row0 + ar) * K;

    for (int k0 = 0; k0 < K; k0 += 16) {
        __syncthreads();
        float4 a = make_float4(0.f, 0.f, 0.f, 0.f);
        if (arow_ok) a = *(const float4*)(Arow + k0 + ak4 * 4);
        As[(ak4 * 4 + 0) * 68 + ar] = a.x;
        As[(ak4 * 4 + 1) * 68 + ar] = a.y;
        As[(ak4 * 4 + 2) * 68 + ar] = a.z;
        As[(ak4 * 4 + 3) * 68 + ar] = a.w;
        #pragma unroll
        for (int i = 0; i < 10; ++i)
            Bs[tid + 256 * i] = B[k0 * 160 + tid + 256 * i];
        __syncthreads();
        #pragma unroll
        for (int k = 0; k < 16; ++k) {
            float4 av = *(const float4*)&As[k * 68 + ty * 4];
            float bv[10];
            #pragma unroll
            for (int i = 0; i < 10; ++i) bv[i] = Bs[k * 160 + tx + 16 * i];
            #pragma unroll
            for (int i = 0; i < 10; ++i) {
                acc[0][i] += av.x * bv[i];
                acc[1][i] += av.y * bv[i];
                acc[2][i] += av.z * bv[i];
                acc[3][i] += av.w * bv[i];
            }
        }
    }
    #pragma unroll
    for (int j = 0; j < 4; ++j) {
        int r = row0 + ty * 4 + j;
        if (r < n) {
            if (OUTMODE == 1) {
                float wr = inv[r];
                #pragma unroll
                for (int i = 0; i < 10; ++i) {
                    float v = acc[j][i] * scv[i] + shv[i];
                    CoutB[(size_t)r * 160 + tx + 16 * i] = f2bf(fmaxf(v, 0.f) * wr);
                }
            } else {
                #pragma unroll
                for (int i = 0; i < 10; ++i) {
                    float v = acc[j][i] * scv[i] + shv[i];
                    CoutF[(size_t)r * 160 + tx + 16 * i] = fmaxf(v, 0.f);
                }
            }
        }
    }
}

// ---------------- mean pool (sorted batch) + MLP head ----------------

__global__ __launch_bounds__(256) void pool_head_kernel(const float* __restrict__ h,
                                                        const int* __restrict__ batch,
                                                        const float* __restrict__ Wc1,
                                                        const float* __restrict__ bc1,
                                                        const float* __restrict__ Wc2,
                                                        const float* __restrict__ bc2,
                                                        float* __restrict__ out, int n) {
    __shared__ float pooled[160];
    __shared__ float z[80];
    __shared__ int range[2];
    int g = blockIdx.x;
    int t = threadIdx.x;
    if (t < 2) {
        int target = g + t;
        int lo = 0, hi = n;
        while (lo < hi) {
            int mid = (lo + hi) >> 1;
            if (batch[mid] < target) lo = mid + 1; else hi = mid;
        }
        range[t] = lo;
    }
    __syncthreads();
    int lo = range[0], hi = range[1];
    if (t < 160) {
        float s = 0.f;
        for (int r = lo; r < hi; ++r) s += h[(size_t)r * 160 + t];
        pooled[t] = s / fmaxf((float)(hi - lo), 1.f);
    }
    __syncthreads();
    if (t < 80) {
        float s = bc1[t];
        for (int k = 0; k < 160; ++k) s += pooled[k] * Wc1[k * 80 + t];
        z[t] = fmaxf(s, 0.f);
    }
    __syncthreads();
    if (t < 2) {
        float s = bc2[t];
        for (int k = 0; k < 80; ++k) s += z[k] * Wc2[k * 2 + t];
        out[g * 2 + t] = s;
    }
}

// ---------------- launch ----------------

static inline size_t align256(size_t x) { return (x + 255) & ~(size_t)255; }

extern "C" void kernel_launch(void* const* d_in, const int* in_sizes, int n_in,
                              void* d_out, int out_size, void* d_ws, size_t ws_size,
                              hipStream_t stream) {
    const float* x   = (const float*)d_in[0];
    const int* ei    = (const int*)d_in[1];
    const int* batch = (const int*)d_in[2];
    const float* W1  = (const float*)d_in[3];
    const float* b1  = (const float*)d_in[4];
    const float* W2  = (const float*)d_in[5];
    const float* b2  = (const float*)d_in[6];
    const float* W3  = (const float*)d_in[7];
    const float* b3  = (const float*)d_in[8];
    const float* g1  = (const float*)d_in[9];
    const float* be1 = (const float*)d_in[10];
    const float* m1  = (const float*)d_in[11];
    const float* v1  = (const float*)d_in[12];
    const float* g2  = (const float*)d_in[13];
    const float* be2 = (const float*)d_in[14];
    const float* m2  = (const float*)d_in[15];
    const float* v2  = (const float*)d_in[16];
    const float* g3  = (const float*)d_in[17];
    const float* be3 = (const float*)d_in[18];
    const float* m3  = (const float*)d_in[19];
    const float* v3  = (const float*)d_in[20];
    const float* Wc1 = (const float*)d_in[21];
    const float* bc1 = (const float*)d_in[22];
    const float* Wc2 = (const float*)d_in[23];
    const float* bc2 = (const float*)d_in[24];
    float* out = (float*)d_out;

    const int N = in_sizes[2];          // 50000
    const int E = in_sizes[1] / 2;      // 1600000
    const int* src = ei;
    const int* dst = ei + E;

    char* w = (char*)d_ws;
    int*   cnt     = (int*)w;             w += align256((size_t)N * 4);
    int*   row_off = (int*)w;             w += align256((size_t)(N + 1) * 4);
    int*   cursor  = (int*)w;             w += align256((size_t)N * 4);
    float* inv     = (float*)w;           w += align256((size_t)N * 4);
    int*   ssrc    = (int*)w;             w += align256((size_t)E * 4);
    float* scsh    = (float*)w;           w += align256((size_t)6 * HDIM * 4);
    float* bufA    = (float*)w;           w += align256((size_t)N * HDIM * 4);   // agg out (GEMM A)
    char*  regionR = w;                   // 32MB region, reused
    unsigned short* xs_bf = (unsigned short*)regionR;                          // N*128*2 = 12.8MB
    unsigned short* hs_bf = (unsigned short*)(regionR + align256((size_t)N * FDIM_IN * 2)); // N*160*2 = 16MB
    float* bufB = (float*)regionR;        // final h3 fp32 (aliases xs_bf/hs_bf, both dead by then)
    float* sc1 = scsh, *sh1 = scsh + 160, *sc2 = scsh + 320, *sh2 = scsh + 480,
         * sc3 = scsh + 640, *sh3 = scsh + 800;

    hipMemsetAsync(cnt, 0, (size_t)N * 4, stream);

    int gE = (E + 255) / 256;
    int gN = (N + 255) / 256;
    hist_kernel<<<gE, 256, 0, stream>>>(dst, cnt, E);
    inv_kernel<<<gN, 256, 0, stream>>>(cnt, inv, N);
    scan_kernel<<<1, 1024, 0, stream>>>(cnt, row_off, cursor, N);
    scatter_kernel<<<gE, 256, 0, stream>>>(src, dst, cursor, ssrc, E);

    prep_kernel<<<1, 256, 0, stream>>>(b1, g1, be1, m1, v1, sc1, sh1);
    prep_kernel<<<1, 256, 0, stream>>>(b2, g2, be2, m2, v2, sc2, sh2);
    prep_kernel<<<1, 256, 0, stream>>>(b3, g3, be3, m3, v3, sc3, sh3);

    int gAgg = (N + 3) / 4;
    int gGemm = (N + 63) / 64;

    // layer 1: xs = bf16(x*inv); agg; GEMM(K=128)+BN+ReLU -> bf16(h*inv)
    scale_bf16_kernel<<<(N * 32 + 255) / 256, 256, 0, stream>>>(x, inv, xs_bf, N);
    agg_bf16_kernel<128><<<gAgg, 256, 0, stream>>>(xs_bf, inv, row_off, ssrc, bufA, N);
    gemm_kernel<128, 1><<<gGemm, 256, 0, stream>>>(bufA, W1, sc1, sh1, inv, nullptr, hs_bf, N);
    // layer 2
    agg_bf16_kernel<160><<<gAgg, 256, 0, stream>>>(hs_bf, inv, row_off, ssrc, bufA, N);
    gemm_kernel<160, 1><<<gGemm, 256, 0, stream>>>(bufA, W2, sc2, sh2, inv, nullptr, hs_bf, N);
    // layer 3: fp32 unscaled h3 for pooling (bufB aliases dead xs/hs region)
    agg_bf16_kernel<160><<<gAgg, 256, 0, stream>>>(hs_bf, inv, row_off, ssrc, bufA, N);
    gemm_kernel<160, 0><<<gGemm, 256, 0, stream>>>(bufA, W3, sc3, sh3, inv, bufB, nullptr, N);

    pool_head_kernel<<<N_GRAPHS, 256, 0, stream>>>(bufB, batch, Wc1, bc1, Wc2, bc2, out, N);
}

// Round 4
// 750.802 us; speedup vs baseline: 1.5120x; 1.1783x over previous
//
#include <hip/hip_runtime.h>

#define N_NODES   50000
#define N_EDGES   1600000
#define FDIM_IN   128
#define HDIM      160
#define N_GRAPHS  512
#define BN_EPS    1e-5f

typedef short  frag8 __attribute__((ext_vector_type(8)));   // 8 x bf16
typedef float  facc4 __attribute__((ext_vector_type(4)));   // 4 x f32

// ---------------- bf16 helpers ----------------

__device__ __forceinline__ unsigned short f2bf(float f) {
    unsigned int u = __float_as_uint(f);
    return (unsigned short)((u + 0x7FFFu + ((u >> 16) & 1u)) >> 16);
}

__device__ __forceinline__ float4 bf4_to_f4(uint2 v) {
    float4 r;
    r.x = __uint_as_float(v.x << 16);
    r.y = __uint_as_float(v.x & 0xFFFF0000u);
    r.z = __uint_as_float(v.y << 16);
    r.w = __uint_as_float(v.y & 0xFFFF0000u);
    return r;
}

// ---------------- edge sort (counting sort by dst) ----------------

__global__ __launch_bounds__(256) void hist_kernel(const int* __restrict__ dst,
                                                   int* __restrict__ cnt, int E) {
    int e = blockIdx.x * 256 + threadIdx.x;
    if (e < E) atomicAdd(&cnt[dst[e]], 1);
}

__global__ __launch_bounds__(256) void inv_kernel(const int* __restrict__ cnt,
                                                  float* __restrict__ inv, int n) {
    int i = blockIdx.x * 256 + threadIdx.x;
    if (i < n) inv[i] = rsqrtf((float)(cnt[i] + 1));   // +1 = self loop
}

__global__ __launch_bounds__(1024) void scan_kernel(const int* __restrict__ cnt,
                                                    int* __restrict__ row_off,
                                                    int* __restrict__ cursor, int n) {
    __shared__ int wavesums[16];
    int t = threadIdx.x;
    int chunk = (n + 1023) >> 10;
    int lo = t * chunk;
    int hi = min(lo + chunk, n);
    int s = 0;
    for (int i = lo; i < hi; ++i) s += cnt[i];
    int lane = t & 63, wid = t >> 6;
    int incl = s;
    #pragma unroll
    for (int off = 1; off < 64; off <<= 1) {
        int v = __shfl_up(incl, off);
        if (lane >= off) incl += v;
    }
    if (lane == 63) wavesums[wid] = incl;
    __syncthreads();
    if (t < 16) {
        int v = wavesums[t];
        int inc2 = v;
        #pragma unroll
        for (int off = 1; off < 16; off <<= 1) {
            int u = __shfl_up(inc2, off);
            if (t >= off) inc2 += u;
        }
        wavesums[t] = inc2 - v;   // exclusive wave offset
    }
    __syncthreads();
    int run = wavesums[wid] + (incl - s);   // exclusive prefix of this chunk
    for (int i = lo; i < hi; ++i) {
        int c = cnt[i];
        row_off[i] = run;
        cursor[i]  = run;
        run += c;
    }
    if (lo < n && hi == n) row_off[n] = run;
}

__global__ __launch_bounds__(256) void scatter_kernel(const int* __restrict__ src,
                                                      const int* __restrict__ dst,
                                                      int* __restrict__ cursor,
                                                      int* __restrict__ ssrc, int E) {
    int e = blockIdx.x * 256 + threadIdx.x;
    if (e < E) {
        int d = dst[e];
        int pos = atomicAdd(&cursor[d], 1);
        ssrc[pos] = src[e];
    }
}

// ---------------- BN fold ----------------

__global__ void prep_kernel(const float* __restrict__ b, const float* __restrict__ g,
                            const float* __restrict__ be, const float* __restrict__ m,
                            const float* __restrict__ v, float* __restrict__ sc,
                            float* __restrict__ sh) {
    int t = threadIdx.x;
    if (t < HDIM) {
        float s = g[t] * rsqrtf(v[t] + BN_EPS);
        sc[t] = s;
        sh[t] = (b[t] - m[t]) * s + be[t];
    }
}

// ---------------- weight pack: W fp32 [K x 160] -> bf16 MFMA B-fragment order ----------------
// frag (t = k-tile of 32, u = n-tile of 16): lane l, j in 0..7 holds
// B[k = t*32 + (l>>4)*8 + j][n = u*16 + (l&15)]; packed idx = ((t*10+u)*64 + l)*8 + j

template <int K>
__global__ __launch_bounds__(256) void pack_w_kernel(const float* __restrict__ W,
                                                     unsigned short* __restrict__ out) {
    int tid = blockIdx.x * 256 + threadIdx.x;
    if (tid >= K * 160) return;
    int j = tid & 7;
    int l = (tid >> 3) & 63;
    int u = (tid >> 9) % 10;
    int t = tid / 5120;
    int k = t * 32 + (l >> 4) * 8 + j;
    int nn = u * 16 + (l & 15);
    out[tid] = f2bf(W[k * 160 + nn]);
}

// ---------------- pre-scale + pack: out_bf16 = x * inv[node]  (C=128) ----------------

__global__ __launch_bounds__(256) void scale_bf16_kernel(const float* __restrict__ x,
                                                         const float* __restrict__ inv,
                                                         unsigned short* __restrict__ out,
                                                         int n) {
    int i = blockIdx.x * 256 + threadIdx.x;      // float4 index over n*32
    if (i < n * 32) {
        int node = i >> 5;
        float w = inv[node];
        float4 v = ((const float4*)x)[i];
        ushort4 o;
        o.x = f2bf(v.x * w); o.y = f2bf(v.y * w);
        o.z = f2bf(v.z * w); o.w = f2bf(v.w * w);
        ((ushort4*)out)[i] = o;
    }
}

// ---------------- aggregation over bf16 pre-scaled operand, bf16 out ----------------
// in_s[bf16] = h*inv (per-row). out[i] = bf16( inv[i] * (sum_{s in nbr(i)} in_s[s] + in_s[i]) )

template <int C>
__global__ __launch_bounds__(256) void agg_bf16_kernel(const unsigned short* __restrict__ in_s,
                                                       const float* __restrict__ inv,
                                                       const int* __restrict__ row_off,
                                                       const int* __restrict__ ssrc,
                                                       unsigned short* __restrict__ out, int n) {
    constexpr int C4 = C / 4;
    int wave = threadIdx.x >> 6;
    int lane = threadIdx.x & 63;
    int node = blockIdx.x * 4 + wave;
    if (node >= n) return;
    int beg = row_off[node], end = row_off[node + 1];
    float inv_i = inv[node];
    const uint2* base = (const uint2*)in_s;      // row stride = C4 uint2s
    float4 acc = make_float4(0.f, 0.f, 0.f, 0.f);
    bool act = lane < C4;
    if (act) acc = bf4_to_f4(base[(size_t)node * C4 + lane]);   // self term
    int j = beg;
    for (; j + 3 < end; j += 4) {
        int s0 = ssrc[j], s1 = ssrc[j + 1], s2 = ssrc[j + 2], s3 = ssrc[j + 3];
        if (act) {
            uint2 r0 = base[(size_t)s0 * C4 + lane];
            uint2 r1 = base[(size_t)s1 * C4 + lane];
            uint2 r2 = base[(size_t)s2 * C4 + lane];
            uint2 r3 = base[(size_t)s3 * C4 + lane];
            float4 v0 = bf4_to_f4(r0), v1 = bf4_to_f4(r1);
            float4 v2 = bf4_to_f4(r2), v3 = bf4_to_f4(r3);
            acc.x += (v0.x + v1.x) + (v2.x + v3.x);
            acc.y += (v0.y + v1.y) + (v2.y + v3.y);
            acc.z += (v0.z + v1.z) + (v2.z + v3.z);
            acc.w += (v0.w + v1.w) + (v2.w + v3.w);
        }
    }
    for (; j < end; ++j) {
        int s0 = ssrc[j];
        if (act) {
            float4 v0 = bf4_to_f4(base[(size_t)s0 * C4 + lane]);
            acc.x += v0.x; acc.y += v0.y; acc.z += v0.z; acc.w += v0.w;
        }
    }
    if (act) {
        ushort4 o;
        o.x = f2bf(acc.x * inv_i); o.y = f2bf(acc.y * inv_i);
        o.z = f2bf(acc.z * inv_i); o.w = f2bf(acc.w * inv_i);
        *(ushort4*)(out + (size_t)node * C + lane * 4) = o;
    }
}

// ---------------- MFMA GEMM: relu((A[n x K]bf16 @ B[K x 160]bf16) * sc + sh) ----------------
// LDS-free. Block = 256 thr = 4 waves; wave owns 16 rows x 160 cols (10 N-tiles).
// OUTMODE 0: fp32 out.  OUTMODE 1: bf16 out scaled by inv[row].

template <int K, int OUTMODE>
__global__ __launch_bounds__(256) void mfma_gemm_kernel(const unsigned short* __restrict__ A,
                                                        const unsigned short* __restrict__ Bp,
                                                        const float* __restrict__ sc,
                                                        const float* __restrict__ sh,
                                                        const float* __restrict__ inv,
                                                        float* __restrict__ CoutF,
                                                        unsigned short* __restrict__ CoutB,
                                                        int n) {
    constexpr int KT = K / 32;
    int tid = threadIdx.x;
    int wave = tid >> 6, lane = tid & 63;
    int row0 = blockIdx.x * 64 + wave * 16;
    int m = lane & 15, q = lane >> 4;

    int arow = row0 + m;
    int arowc = (arow < n) ? arow : (n - 1);
    const frag8* Abase = (const frag8*)(A + (size_t)arowc * K);   // frag idx = t*4 + q
    const frag8* Bbase = (const frag8*)Bp;                        // frag idx = (t*10+u)*64 + lane

    facc4 acc[10];
    #pragma unroll
    for (int u = 0; u < 10; ++u) acc[u] = (facc4){0.f, 0.f, 0.f, 0.f};

    #pragma unroll
    for (int t = 0; t < KT; ++t) {
        frag8 af = Abase[t * 4 + q];
        #pragma unroll
        for (int u = 0; u < 10; ++u) {
            frag8 bf = Bbase[(t * 10 + u) * 64 + lane];
            acc[u] = __builtin_amdgcn_mfma_f32_16x16x32_bf16(af, bf, acc[u], 0, 0, 0);
        }
    }

    // D layout: col = lane&15 (within tile), row = q*4 + reg
    #pragma unroll
    for (int u = 0; u < 10; ++u) {
        int c = u * 16 + m;
        float scv = sc[c], shv = sh[c];
        #pragma unroll
        for (int r = 0; r < 4; ++r) {
            int rr = row0 + q * 4 + r;
            if (rr < n) {
                float v = fmaxf(acc[u][r] * scv + shv, 0.f);
                if (OUTMODE == 1) {
                    CoutB[(size_t)rr * 160 + c] = f2bf(v * inv[rr]);
                } else {
                    CoutF[(size_t)rr * 160 + c] = v;
                }
            }
        }
    }
}

// ---------------- mean pool (sorted batch) + MLP head ----------------

__global__ __launch_bounds__(256) void pool_head_kernel(const float* __restrict__ h,
                                                        const int* __restrict__ batch,
                                                        const float* __restrict__ Wc1,
                                                        const float* __restrict__ bc1,
                                                        const float* __restrict__ Wc2,
                                                        const float* __restrict__ bc2,
                                                        float* __restrict__ out, int n) {
    __shared__ float pooled[160];
    __shared__ float z[80];
    __shared__ int range[2];
    int g = blockIdx.x;
    int t = threadIdx.x;
    if (t < 2) {
        int target = g + t;
        int lo = 0, hi = n;
        while (lo < hi) {
            int mid = (lo + hi) >> 1;
            if (batch[mid] < target) lo = mid + 1; else hi = mid;
        }
        range[t] = lo;
    }
    __syncthreads();
    int lo = range[0], hi = range[1];
    if (t < 160) {
        float s = 0.f;
        for (int r = lo; r < hi; ++r) s += h[(size_t)r * 160 + t];
        pooled[t] = s / fmaxf((float)(hi - lo), 1.f);
    }
    __syncthreads();
    if (t < 80) {
        float s = bc1[t];
        for (int k = 0; k < 160; ++k) s += pooled[k] * Wc1[k * 80 + t];
        z[t] = fmaxf(s, 0.f);
    }
    __syncthreads();
    if (t < 2) {
        float s = bc2[t];
        for (int k = 0; k < 80; ++k) s += z[k] * Wc2[k * 2 + t];
        out[g * 2 + t] = s;
    }
}

// ---------------- launch ----------------

static inline size_t align256(size_t x) { return (x + 255) & ~(size_t)255; }

extern "C" void kernel_launch(void* const* d_in, const int* in_sizes, int n_in,
                              void* d_out, int out_size, void* d_ws, size_t ws_size,
                              hipStream_t stream) {
    const float* x   = (const float*)d_in[0];
    const int* ei    = (const int*)d_in[1];
    const int* batch = (const int*)d_in[2];
    const float* W1  = (const float*)d_in[3];
    const float* b1  = (const float*)d_in[4];
    const float* W2  = (const float*)d_in[5];
    const float* b2  = (const float*)d_in[6];
    const float* W3  = (const float*)d_in[7];
    const float* b3  = (const float*)d_in[8];
    const float* g1  = (const float*)d_in[9];
    const float* be1 = (const float*)d_in[10];
    const float* m1  = (const float*)d_in[11];
    const float* v1  = (const float*)d_in[12];
    const float* g2  = (const float*)d_in[13];
    const float* be2 = (const float*)d_in[14];
    const float* m2  = (const float*)d_in[15];
    const float* v2  = (const float*)d_in[16];
    const float* g3  = (const float*)d_in[17];
    const float* be3 = (const float*)d_in[18];
    const float* m3  = (const float*)d_in[19];
    const float* v3  = (const float*)d_in[20];
    const float* Wc1 = (const float*)d_in[21];
    const float* bc1 = (const float*)d_in[22];
    const float* Wc2 = (const float*)d_in[23];
    const float* bc2 = (const float*)d_in[24];
    float* out = (float*)d_out;

    const int N = in_sizes[2];          // 50000
    const int E = in_sizes[1] / 2;      // 1600000
    const int* src = ei;
    const int* dst = ei + E;

    char* w = (char*)d_ws;
    int*   cnt     = (int*)w;             w += align256((size_t)N * 4);
    int*   row_off = (int*)w;             w += align256((size_t)(N + 1) * 4);
    int*   cursor  = (int*)w;             w += align256((size_t)N * 4);
    float* inv     = (float*)w;           w += align256((size_t)N * 4);
    int*   ssrc    = (int*)w;             w += align256((size_t)E * 4);
    float* scsh    = (float*)w;           w += align256((size_t)6 * HDIM * 4);
    unsigned short* W1p = (unsigned short*)w;  w += align256((size_t)FDIM_IN * HDIM * 2);
    unsigned short* W2p = (unsigned short*)w;  w += align256((size_t)HDIM * HDIM * 2);
    unsigned short* W3p = (unsigned short*)w;  w += align256((size_t)HDIM * HDIM * 2);
    unsigned short* bufA_bf = (unsigned short*)w;  w += align256((size_t)N * HDIM * 2);  // agg out (GEMM A)
    char* regionR = w;                    // reused region (>= 32MB needed for bufB)
    unsigned short* xs_bf = (unsigned short*)regionR;                           // N*128*2
    unsigned short* hs_bf = (unsigned short*)(regionR + align256((size_t)N * FDIM_IN * 2)); // N*160*2
    float* bufB = (float*)regionR;        // final h3 fp32 (aliases xs/hs, both dead by then)
    float* sc1 = scsh, *sh1 = scsh + 160, *sc2 = scsh + 320, *sh2 = scsh + 480,
         * sc3 = scsh + 640, *sh3 = scsh + 800;

    hipMemsetAsync(cnt, 0, (size_t)N * 4, stream);

    int gE = (E + 255) / 256;
    int gN = (N + 255) / 256;
    hist_kernel<<<gE, 256, 0, stream>>>(dst, cnt, E);
    inv_kernel<<<gN, 256, 0, stream>>>(cnt, inv, N);
    scan_kernel<<<1, 1024, 0, stream>>>(cnt, row_off, cursor, N);
    scatter_kernel<<<gE, 256, 0, stream>>>(src, dst, cursor, ssrc, E);

    prep_kernel<<<1, 256, 0, stream>>>(b1, g1, be1, m1, v1, sc1, sh1);
    prep_kernel<<<1, 256, 0, stream>>>(b2, g2, be2, m2, v2, sc2, sh2);
    prep_kernel<<<1, 256, 0, stream>>>(b3, g3, be3, m3, v3, sc3, sh3);
    pack_w_kernel<128><<<(128 * 160 + 255) / 256, 256, 0, stream>>>(W1, W1p);
    pack_w_kernel<160><<<(160 * 160 + 255) / 256, 256, 0, stream>>>(W2, W2p);
    pack_w_kernel<160><<<(160 * 160 + 255) / 256, 256, 0, stream>>>(W3, W3p);

    int gAgg = (N + 3) / 4;
    int gGemm = (N + 63) / 64;

    // layer 1: xs = bf16(x*inv); agg; MFMA GEMM(K=128)+BN+ReLU -> bf16(h*inv)
    scale_bf16_kernel<<<(N * 32 + 255) / 256, 256, 0, stream>>>(x, inv, xs_bf, N);
    agg_bf16_kernel<128><<<gAgg, 256, 0, stream>>>(xs_bf, inv, row_off, ssrc, bufA_bf, N);
    mfma_gemm_kernel<128, 1><<<gGemm, 256, 0, stream>>>(bufA_bf, W1p, sc1, sh1, inv, nullptr, hs_bf, N);
    // layer 2
    agg_bf16_kernel<160><<<gAgg, 256, 0, stream>>>(hs_bf, inv, row_off, ssrc, bufA_bf, N);
    mfma_gemm_kernel<160, 1><<<gGemm, 256, 0, stream>>>(bufA_bf, W2p, sc2, sh2, inv, nullptr, hs_bf, N);
    // layer 3: fp32 unscaled h3 for pooling (bufB aliases dead xs/hs region)
    agg_bf16_kernel<160><<<gAgg, 256, 0, stream>>>(hs_bf, inv, row_off, ssrc, bufA_bf, N);
    mfma_gemm_kernel<160, 0><<<gGemm, 256, 0, stream>>>(bufA_bf, W3p, sc3, sh3, inv, bufB, nullptr, N);

    pool_head_kernel<<<N_GRAPHS, 256, 0, stream>>>(bufB, batch, Wc1, bc1, Wc2, bc2, out, N);
}

// Round 5
// 525.289 us; speedup vs baseline: 2.1612x; 1.4293x over previous
//
#include <hip/hip_runtime.h>

#define N_NODES   50000
#define N_EDGES   1600000
#define FDIM_IN   128
#define HDIM      160
#define N_GRAPHS  512
#define BN_EPS    1e-5f
#define NBKT_MAX  128           // coarse buckets of 512 nodes (N<=65536)

typedef short  frag8 __attribute__((ext_vector_type(8)));   // 8 x bf16
typedef float  facc4 __attribute__((ext_vector_type(4)));   // 4 x f32

// ---------------- bf16 helpers ----------------

__device__ __forceinline__ unsigned short f2bf(float f) {
    unsigned int u = __float_as_uint(f);
    return (unsigned short)((u + 0x7FFFu + ((u >> 16) & 1u)) >> 16);
}

__device__ __forceinline__ float4 bf4_to_f4(uint2 v) {
    float4 r;
    r.x = __uint_as_float(v.x << 16);
    r.y = __uint_as_float(v.x & 0xFFFF0000u);
    r.z = __uint_as_float(v.y << 16);
    r.w = __uint_as_float(v.y & 0xFFFF0000u);
    return r;
}

// ---------------- two-level counting sort by dst ----------------

__global__ __launch_bounds__(256) void coarse_hist_kernel(const int* __restrict__ dst,
                                                          int* __restrict__ cg, int E) {
    __shared__ int h[NBKT_MAX];
    int tid = threadIdx.x;
    if (tid < NBKT_MAX) h[tid] = 0;
    __syncthreads();
    for (int e = blockIdx.x * 256 + tid; e < E; e += gridDim.x * 256)
        atomicAdd(&h[dst[e] >> 9], 1);
    __syncthreads();
    if (tid < NBKT_MAX && h[tid]) atomicAdd(&cg[tid], h[tid]);
}

__global__ __launch_bounds__(128) void coarse_scan_kernel(const int* __restrict__ cg,
                                                          int* __restrict__ bucket_base,
                                                          int* __restrict__ bucket_cursor) {
    __shared__ int h[NBKT_MAX];
    int t = threadIdx.x;
    h[t] = cg[t];
    __syncthreads();
    if (t == 0) {
        int run = 0;
        for (int i = 0; i < NBKT_MAX; ++i) { int c = h[i]; h[i] = run; run += c; }
    }
    __syncthreads();
    bucket_base[t] = h[t];
    bucket_cursor[t] = h[t];
    if (t == 0) bucket_base[NBKT_MAX] = h[NBKT_MAX - 1] + cg[NBKT_MAX - 1];
}

// level 1: partition (src,dst) pairs into coarse-bucket-contiguous regions
__global__ __launch_bounds__(256) void part_kernel(const int* __restrict__ src,
                                                   const int* __restrict__ dst,
                                                   int* __restrict__ bucket_cursor,
                                                   uint2* __restrict__ pairs, int E) {
    __shared__ int bcnt[NBKT_MAX], bbase[NBKT_MAX], lc[NBKT_MAX];
    int tid = threadIdx.x;
    int per = (E + gridDim.x - 1) / gridDim.x;
    int beg = blockIdx.x * per;
    int end = min(beg + per, E);
    if (tid < NBKT_MAX) { bcnt[tid] = 0; lc[tid] = 0; }
    __syncthreads();
    for (int e = beg + tid; e < end; e += 256)
        atomicAdd(&bcnt[dst[e] >> 9], 1);
    __syncthreads();
    if (tid < NBKT_MAX)
        bbase[tid] = bcnt[tid] ? atomicAdd(&bucket_cursor[tid], bcnt[tid]) : 0;
    __syncthreads();
    for (int e = beg + tid; e < end; e += 256) {
        int d = dst[e];
        int b = d >> 9;
        int pos = bbase[b] + atomicAdd(&lc[b], 1);
        pairs[pos] = make_uint2((unsigned)src[e], (unsigned)d);
    }
}

// level 2: per-bucket exact CSR build + local scatter (dest window ~64KB -> L2-resident)
__global__ __launch_bounds__(1024) void bucket_csr_kernel(const uint2* __restrict__ pairs,
                                                          const int* __restrict__ bucket_base,
                                                          int* __restrict__ row_off,
                                                          float* __restrict__ inv,
                                                          int* __restrict__ ssrc, int n) {
    __shared__ int h[512];
    __shared__ int ws[8];
    int tid = threadIdx.x;
    int b = blockIdx.x;
    int node0 = b << 9;
    int beg = bucket_base[b], end = bucket_base[b + 1];
    if (tid < 512) h[tid] = 0;
    __syncthreads();
    for (int j = beg + tid; j < end; j += 1024)
        atomicAdd(&h[pairs[j].y & 511], 1);
    __syncthreads();
    int cntv = (tid < 512) ? h[tid] : 0;
    __syncthreads();
    // inclusive wave scan over 8 waves (tid<512 covers all counters)
    int lane = tid & 63, wid = tid >> 6;
    int incl = cntv;
    #pragma unroll
    for (int off = 1; off < 64; off <<= 1) {
        int u = __shfl_up(incl, off);
        if (lane >= off) incl += u;
    }
    if (tid < 512 && lane == 63) ws[wid] = incl;
    __syncthreads();
    if (tid == 0) {
        int r = 0;
        #pragma unroll
        for (int i = 0; i < 8; ++i) { int t = ws[i]; ws[i] = r; r += t; }
    }
    __syncthreads();
    int excl = (tid < 512) ? (ws[wid] + incl - cntv) : 0;
    if (tid < 512) {
        int node = node0 + tid;
        if (node < n) {
            row_off[node] = beg + excl;
            inv[node] = rsqrtf((float)(cntv + 1));   // +1 = self loop
        }
        h[tid] = excl;
    }
    if (tid == 0 && (node0 + 512) >= n) row_off[n] = end;
    __syncthreads();
    for (int j = beg + tid; j < end; j += 1024) {
        uint2 p = pairs[j];
        int pos = beg + atomicAdd(&h[p.y & 511], 1);
        ssrc[pos] = (int)p.x;
    }
}

// ---------------- BN fold ----------------

__global__ void prep_kernel(const float* __restrict__ b, const float* __restrict__ g,
                            const float* __restrict__ be, const float* __restrict__ m,
                            const float* __restrict__ v, float* __restrict__ sc,
                            float* __restrict__ sh) {
    int t = threadIdx.x;
    if (t < HDIM) {
        float s = g[t] * rsqrtf(v[t] + BN_EPS);
        sc[t] = s;
        sh[t] = (b[t] - m[t]) * s + be[t];
    }
}

// ---------------- weight pack: W fp32 [K x 160] -> bf16 MFMA B-fragment order ----------------

template <int K>
__global__ __launch_bounds__(256) void pack_w_kernel(const float* __restrict__ W,
                                                     unsigned short* __restrict__ out) {
    int tid = blockIdx.x * 256 + threadIdx.x;
    if (tid >= K * 160) return;
    int j = tid & 7;
    int l = (tid >> 3) & 63;
    int u = (tid >> 9) % 10;
    int t = tid / 5120;
    int k = t * 32 + (l >> 4) * 8 + j;
    int nn = u * 16 + (l & 15);
    out[tid] = f2bf(W[k * 160 + nn]);
}

// ---------------- pre-scale + pack: out_bf16 = x * inv[node]  (C=128) ----------------

__global__ __launch_bounds__(256) void scale_bf16_kernel(const float* __restrict__ x,
                                                         const float* __restrict__ inv,
                                                         unsigned short* __restrict__ out,
                                                         int n) {
    int i = blockIdx.x * 256 + threadIdx.x;      // float4 index over n*32
    if (i < n * 32) {
        int node = i >> 5;
        float w = inv[node];
        float4 v = ((const float4*)x)[i];
        ushort4 o;
        o.x = f2bf(v.x * w); o.y = f2bf(v.y * w);
        o.z = f2bf(v.z * w); o.w = f2bf(v.w * w);
        ((ushort4*)out)[i] = o;
    }
}

// ---------------- aggregation over bf16 pre-scaled operand, bf16 out ----------------

template <int C>
__global__ __launch_bounds__(256) void agg_bf16_kernel(const unsigned short* __restrict__ in_s,
                                                       const float* __restrict__ inv,
                                                       const int* __restrict__ row_off,
                                                       const int* __restrict__ ssrc,
                                                       unsigned short* __restrict__ out, int n) {
    constexpr int C4 = C / 4;
    int wave = threadIdx.x >> 6;
    int lane = threadIdx.x & 63;
    int node = blockIdx.x * 4 + wave;
    if (node >= n) return;
    int beg = row_off[node], end = row_off[node + 1];
    float inv_i = inv[node];
    const uint2* base = (const uint2*)in_s;      // row stride = C4 uint2s
    float4 acc = make_float4(0.f, 0.f, 0.f, 0.f);
    bool act = lane < C4;
    if (act) acc = bf4_to_f4(base[(size_t)node * C4 + lane]);   // self term
    int j = beg;
    for (; j + 3 < end; j += 4) {
        int s0 = ssrc[j], s1 = ssrc[j + 1], s2 = ssrc[j + 2], s3 = ssrc[j + 3];
        if (act) {
            uint2 r0 = base[(size_t)s0 * C4 + lane];
            uint2 r1 = base[(size_t)s1 * C4 + lane];
            uint2 r2 = base[(size_t)s2 * C4 + lane];
            uint2 r3 = base[(size_t)s3 * C4 + lane];
            float4 v0 = bf4_to_f4(r0), v1 = bf4_to_f4(r1);
            float4 v2 = bf4_to_f4(r2), v3 = bf4_to_f4(r3);
            acc.x += (v0.x + v1.x) + (v2.x + v3.x);
            acc.y += (v0.y + v1.y) + (v2.y + v3.y);
            acc.z += (v0.z + v1.z) + (v2.z + v3.z);
            acc.w += (v0.w + v1.w) + (v2.w + v3.w);
        }
    }
    for (; j < end; ++j) {
        int s0 = ssrc[j];
        if (act) {
            float4 v0 = bf4_to_f4(base[(size_t)s0 * C4 + lane]);
            acc.x += v0.x; acc.y += v0.y; acc.z += v0.z; acc.w += v0.w;
        }
    }
    if (act) {
        ushort4 o;
        o.x = f2bf(acc.x * inv_i); o.y = f2bf(acc.y * inv_i);
        o.z = f2bf(acc.z * inv_i); o.w = f2bf(acc.w * inv_i);
        *(ushort4*)(out + (size_t)node * C + lane * 4) = o;
    }
}

// ---------------- MFMA GEMM: relu((A[n x K]bf16 @ B[K x 160]bf16) * sc + sh) ----------------

template <int K, int OUTMODE>
__global__ __launch_bounds__(256) void mfma_gemm_kernel(const unsigned short* __restrict__ A,
                                                        const unsigned short* __restrict__ Bp,
                                                        const float* __restrict__ sc,
                                                        const float* __restrict__ sh,
                                                        const float* __restrict__ inv,
                                                        float* __restrict__ CoutF,
                                                        unsigned short* __restrict__ CoutB,
                                                        int n) {
    constexpr int KT = K / 32;
    int tid = threadIdx.x;
    int wave = tid >> 6, lane = tid & 63;
    int row0 = blockIdx.x * 64 + wave * 16;
    int m = lane & 15, q = lane >> 4;

    int arow = row0 + m;
    int arowc = (arow < n) ? arow : (n - 1);
    const frag8* Abase = (const frag8*)(A + (size_t)arowc * K);   // frag idx = t*4 + q
    const frag8* Bbase = (const frag8*)Bp;                        // frag idx = (t*10+u)*64 + lane

    facc4 acc[10];
    #pragma unroll
    for (int u = 0; u < 10; ++u) acc[u] = (facc4){0.f, 0.f, 0.f, 0.f};

    #pragma unroll
    for (int t = 0; t < KT; ++t) {
        frag8 af = Abase[t * 4 + q];
        #pragma unroll
        for (int u = 0; u < 10; ++u) {
            frag8 bf = Bbase[(t * 10 + u) * 64 + lane];
            acc[u] = __builtin_amdgcn_mfma_f32_16x16x32_bf16(af, bf, acc[u], 0, 0, 0);
        }
    }

    // D layout: col = lane&15 (within tile), row = q*4 + reg
    #pragma unroll
    for (int u = 0; u < 10; ++u) {
        int c = u * 16 + m;
        float scv = sc[c], shv = sh[c];
        #pragma unroll
        for (int r = 0; r < 4; ++r) {
            int rr = row0 + q * 4 + r;
            if (rr < n) {
                float v = fmaxf(acc[u][r] * scv + shv, 0.f);
                if (OUTMODE == 1) {
                    CoutB[(size_t)rr * 160 + c] = f2bf(v * inv[rr]);
                } else {
                    CoutF[(size_t)rr * 160 + c] = v;
                }
            }
        }
    }
}

// ---------------- mean pool (sorted batch) + MLP head ----------------

__global__ __launch_bounds__(256) void pool_head_kernel(const float* __restrict__ h,
                                                        const int* __restrict__ batch,
                                                        const float* __restrict__ Wc1,
                                                        const float* __restrict__ bc1,
                                                        const float* __restrict__ Wc2,
                                                        const float* __restrict__ bc2,
                                                        float* __restrict__ out, int n) {
    __shared__ float pooled[160];
    __shared__ float z[80];
    __shared__ int range[2];
    int g = blockIdx.x;
    int t = threadIdx.x;
    if (t < 2) {
        int target = g + t;
        int lo = 0, hi = n;
        while (lo < hi) {
            int mid = (lo + hi) >> 1;
            if (batch[mid] < target) lo = mid + 1; else hi = mid;
        }
        range[t] = lo;
    }
    __syncthreads();
    int lo = range[0], hi = range[1];
    if (t < 160) {
        float s = 0.f;
        for (int r = lo; r < hi; ++r) s += h[(size_t)r * 160 + t];
        pooled[t] = s / fmaxf((float)(hi - lo), 1.f);
    }
    __syncthreads();
    if (t < 80) {
        float s = bc1[t];
        for (int k = 0; k < 160; ++k) s += pooled[k] * Wc1[k * 80 + t];
        z[t] = fmaxf(s, 0.f);
    }
    __syncthreads();
    if (t < 2) {
        float s = bc2[t];
        for (int k = 0; k < 80; ++k) s += z[k] * Wc2[k * 2 + t];
        out[g * 2 + t] = s;
    }
}

// ---------------- launch ----------------

static inline size_t align256(size_t x) { return (x + 255) & ~(size_t)255; }

extern "C" void kernel_launch(void* const* d_in, const int* in_sizes, int n_in,
                              void* d_out, int out_size, void* d_ws, size_t ws_size,
                              hipStream_t stream) {
    const float* x   = (const float*)d_in[0];
    const int* ei    = (const int*)d_in[1];
    const int* batch = (const int*)d_in[2];
    const float* W1  = (const float*)d_in[3];
    const float* b1  = (const float*)d_in[4];
    const float* W2  = (const float*)d_in[5];
    const float* b2  = (const float*)d_in[6];
    const float* W3  = (const float*)d_in[7];
    const float* b3  = (const float*)d_in[8];
    const float* g1  = (const float*)d_in[9];
    const float* be1 = (const float*)d_in[10];
    const float* m1  = (const float*)d_in[11];
    const float* v1  = (const float*)d_in[12];
    const float* g2  = (const float*)d_in[13];
    const float* be2 = (const float*)d_in[14];
    const float* m2  = (const float*)d_in[15];
    const float* v2  = (const float*)d_in[16];
    const float* g3  = (const float*)d_in[17];
    const float* be3 = (const float*)d_in[18];
    const float* m3  = (const float*)d_in[19];
    const float* v3  = (const float*)d_in[20];
    const float* Wc1 = (const float*)d_in[21];
    const float* bc1 = (const float*)d_in[22];
    const float* Wc2 = (const float*)d_in[23];
    const float* bc2 = (const float*)d_in[24];
    float* out = (float*)d_out;

    const int N = in_sizes[2];          // 50000
    const int E = in_sizes[1] / 2;      // 1600000
    const int* src = ei;
    const int* dst = ei + E;

    char* w = (char*)d_ws;
    int*   row_off = (int*)w;             w += align256((size_t)(N + 1) * 4);
    float* inv     = (float*)w;           w += align256((size_t)N * 4);
    int*   ssrc    = (int*)w;             w += align256((size_t)E * 4);
    uint2* pairs   = (uint2*)w;           w += align256((size_t)E * 8);
    int*   cg      = (int*)w;             w += align256((size_t)NBKT_MAX * 4);
    int*   bucket_base   = (int*)w;       w += align256((size_t)(NBKT_MAX + 1) * 4);
    int*   bucket_cursor = (int*)w;       w += align256((size_t)NBKT_MAX * 4);
    float* scsh    = (float*)w;           w += align256((size_t)6 * HDIM * 4);
    unsigned short* W1p = (unsigned short*)w;  w += align256((size_t)FDIM_IN * HDIM * 2);
    unsigned short* W2p = (unsigned short*)w;  w += align256((size_t)HDIM * HDIM * 2);
    unsigned short* W3p = (unsigned short*)w;  w += align256((size_t)HDIM * HDIM * 2);
    unsigned short* bufA_bf = (unsigned short*)w;  w += align256((size_t)N * HDIM * 2);
    char* regionR = w;                    // reused region
    unsigned short* xs_bf = (unsigned short*)regionR;                           // N*128*2
    unsigned short* hs_bf = (unsigned short*)(regionR + align256((size_t)N * FDIM_IN * 2)); // N*160*2
    float* bufB = (float*)regionR;        // final h3 fp32 (aliases xs/hs, both dead by then)
    float* sc1 = scsh, *sh1 = scsh + 160, *sc2 = scsh + 320, *sh2 = scsh + 480,
         * sc3 = scsh + 640, *sh3 = scsh + 800;

    hipMemsetAsync(cg, 0, (size_t)NBKT_MAX * 4, stream);

    // two-level counting sort by dst -> row_off, ssrc, inv
    coarse_hist_kernel<<<256, 256, 0, stream>>>(dst, cg, E);
    coarse_scan_kernel<<<1, 128, 0, stream>>>(cg, bucket_base, bucket_cursor);
    part_kernel<<<256, 256, 0, stream>>>(src, dst, bucket_cursor, pairs, E);
    int nbkt = (N + 511) >> 9;
    bucket_csr_kernel<<<nbkt, 1024, 0, stream>>>(pairs, bucket_base, row_off, inv, ssrc, N);

    prep_kernel<<<1, 256, 0, stream>>>(b1, g1, be1, m1, v1, sc1, sh1);
    prep_kernel<<<1, 256, 0, stream>>>(b2, g2, be2, m2, v2, sc2, sh2);
    prep_kernel<<<1, 256, 0, stream>>>(b3, g3, be3, m3, v3, sc3, sh3);
    pack_w_kernel<128><<<(128 * 160 + 255) / 256, 256, 0, stream>>>(W1, W1p);
    pack_w_kernel<160><<<(160 * 160 + 255) / 256, 256, 0, stream>>>(W2, W2p);
    pack_w_kernel<160><<<(160 * 160 + 255) / 256, 256, 0, stream>>>(W3, W3p);

    int gAgg = (N + 3) / 4;
    int gGemm = (N + 63) / 64;

    // layer 1: xs = bf16(x*inv); agg; MFMA GEMM(K=128)+BN+ReLU -> bf16(h*inv)
    scale_bf16_kernel<<<(N * 32 + 255) / 256, 256, 0, stream>>>(x, inv, xs_bf, N);
    agg_bf16_kernel<128><<<gAgg, 256, 0, stream>>>(xs_bf, inv, row_off, ssrc, bufA_bf, N);
    mfma_gemm_kernel<128, 1><<<gGemm, 256, 0, stream>>>(bufA_bf, W1p, sc1, sh1, inv, nullptr, hs_bf, N);
    // layer 2
    agg_bf16_kernel<160><<<gAgg, 256, 0, stream>>>(hs_bf, inv, row_off, ssrc, bufA_bf, N);
    mfma_gemm_kernel<160, 1><<<gGemm, 256, 0, stream>>>(bufA_bf, W2p, sc2, sh2, inv, nullptr, hs_bf, N);
    // layer 3: fp32 unscaled h3 for pooling (bufB aliases dead xs/hs region)
    agg_bf16_kernel<160><<<gAgg, 256, 0, stream>>>(hs_bf, inv, row_off, ssrc, bufA_bf, N);
    mfma_gemm_kernel<160, 0><<<gGemm, 256, 0, stream>>>(bufA_bf, W3p, sc3, sh3, inv, bufB, nullptr, N);

    pool_head_kernel<<<N_GRAPHS, 256, 0, stream>>>(bufB, batch, Wc1, bc1, Wc2, bc2, out, N);
}

// Round 6
// 476.094 us; speedup vs baseline: 2.3845x; 1.1033x over previous
//
#include <hip/hip_runtime.h>

#define N_NODES   50000
#define N_EDGES   1600000
#define FDIM_IN   128
#define HDIM      160
#define N_GRAPHS  512
#define BN_EPS    1e-5f
#define NBKT_MAX  128           // coarse buckets of 512 nodes (N<=65536)

typedef short  frag8 __attribute__((ext_vector_type(8)));   // 8 x bf16
typedef float  facc4 __attribute__((ext_vector_type(4)));   // 4 x f32

// ---------------- bf16 helpers ----------------

__device__ __forceinline__ unsigned short f2bf(float f) {
    unsigned int u = __float_as_uint(f);
    return (unsigned short)((u + 0x7FFFu + ((u >> 16) & 1u)) >> 16);
}

__device__ __forceinline__ unsigned int pack2(float lo, float hi) {
    return (unsigned int)f2bf(lo) | ((unsigned int)f2bf(hi) << 16);
}

__device__ __forceinline__ void addpk(float* acc, uint4 r) {
    acc[0] += __uint_as_float(r.x << 16);
    acc[1] += __uint_as_float(r.x & 0xFFFF0000u);
    acc[2] += __uint_as_float(r.y << 16);
    acc[3] += __uint_as_float(r.y & 0xFFFF0000u);
    acc[4] += __uint_as_float(r.z << 16);
    acc[5] += __uint_as_float(r.z & 0xFFFF0000u);
    acc[6] += __uint_as_float(r.w << 16);
    acc[7] += __uint_as_float(r.w & 0xFFFF0000u);
}

// ---------------- two-level counting sort by dst ----------------

__global__ __launch_bounds__(256) void coarse_hist_kernel(const int* __restrict__ dst,
                                                          int* __restrict__ cg, int E) {
    __shared__ int h[NBKT_MAX];
    int tid = threadIdx.x;
    if (tid < NBKT_MAX) h[tid] = 0;
    __syncthreads();
    for (int e = blockIdx.x * 256 + tid; e < E; e += gridDim.x * 256)
        atomicAdd(&h[dst[e] >> 9], 1);
    __syncthreads();
    if (tid < NBKT_MAX && h[tid]) atomicAdd(&cg[tid], h[tid]);
}

__global__ __launch_bounds__(128) void coarse_scan_kernel(const int* __restrict__ cg,
                                                          int* __restrict__ bucket_base,
                                                          int* __restrict__ bucket_cursor) {
    __shared__ int h[NBKT_MAX];
    int t = threadIdx.x;
    h[t] = cg[t];
    __syncthreads();
    if (t == 0) {
        int run = 0;
        for (int i = 0; i < NBKT_MAX; ++i) { int c = h[i]; h[i] = run; run += c; }
    }
    __syncthreads();
    bucket_base[t] = h[t];
    bucket_cursor[t] = h[t];
    if (t == 0) bucket_base[NBKT_MAX] = h[NBKT_MAX - 1] + cg[NBKT_MAX - 1];
}

// level 1: partition packed (src<<9 | dst&511) into coarse-bucket-contiguous regions
__global__ __launch_bounds__(256) void part_kernel(const int* __restrict__ src,
                                                   const int* __restrict__ dst,
                                                   int* __restrict__ bucket_cursor,
                                                   unsigned int* __restrict__ pairs, int E) {
    __shared__ int bcnt[NBKT_MAX], bbase[NBKT_MAX], lc[NBKT_MAX];
    int tid = threadIdx.x;
    int per = (E + gridDim.x - 1) / gridDim.x;
    int beg = blockIdx.x * per;
    int end = min(beg + per, E);
    if (tid < NBKT_MAX) { bcnt[tid] = 0; lc[tid] = 0; }
    __syncthreads();
    for (int e = beg + tid; e < end; e += 256)
        atomicAdd(&bcnt[dst[e] >> 9], 1);
    __syncthreads();
    if (tid < NBKT_MAX)
        bbase[tid] = bcnt[tid] ? atomicAdd(&bucket_cursor[tid], bcnt[tid]) : 0;
    __syncthreads();
    for (int e = beg + tid; e < end; e += 256) {
        int d = dst[e];
        int b = d >> 9;
        int pos = bbase[b] + atomicAdd(&lc[b], 1);
        pairs[pos] = ((unsigned int)src[e] << 9) | (unsigned int)(d & 511);
    }
}

// level 2: per-bucket exact CSR build + local scatter (dest window L2-resident)
__global__ __launch_bounds__(1024) void bucket_csr_kernel(const unsigned int* __restrict__ pairs,
                                                          const int* __restrict__ bucket_base,
                                                          int* __restrict__ row_off,
                                                          float* __restrict__ inv,
                                                          int* __restrict__ ssrc, int n) {
    __shared__ int h[512];
    __shared__ int ws[8];
    int tid = threadIdx.x;
    int b = blockIdx.x;
    int node0 = b << 9;
    int beg = bucket_base[b], end = bucket_base[b + 1];
    if (tid < 512) h[tid] = 0;
    __syncthreads();
    for (int j = beg + tid; j < end; j += 1024)
        atomicAdd(&h[pairs[j] & 511], 1);
    __syncthreads();
    int cntv = (tid < 512) ? h[tid] : 0;
    __syncthreads();
    int lane = tid & 63, wid = tid >> 6;
    int incl = cntv;
    #pragma unroll
    for (int off = 1; off < 64; off <<= 1) {
        int u = __shfl_up(incl, off);
        if (lane >= off) incl += u;
    }
    if (tid < 512 && lane == 63) ws[wid] = incl;
    __syncthreads();
    if (tid == 0) {
        int r = 0;
        #pragma unroll
        for (int i = 0; i < 8; ++i) { int t = ws[i]; ws[i] = r; r += t; }
    }
    __syncthreads();
    int excl = (tid < 512) ? (ws[wid] + incl - cntv) : 0;
    if (tid < 512) {
        int node = node0 + tid;
        if (node < n) {
            row_off[node] = beg + excl;
            inv[node] = rsqrtf((float)(cntv + 1));   // +1 = self loop
        }
        h[tid] = excl;
    }
    if (tid == 0 && (node0 + 512) >= n) row_off[n] = end;
    __syncthreads();
    for (int j = beg + tid; j < end; j += 1024) {
        unsigned int p = pairs[j];
        int pos = beg + atomicAdd(&h[p & 511], 1);
        ssrc[pos] = (int)(p >> 9);
    }
}

// ---------------- BN fold ----------------

__global__ void prep_kernel(const float* __restrict__ b, const float* __restrict__ g,
                            const float* __restrict__ be, const float* __restrict__ m,
                            const float* __restrict__ v, float* __restrict__ sc,
                            float* __restrict__ sh) {
    int t = threadIdx.x;
    if (t < HDIM) {
        float s = g[t] * rsqrtf(v[t] + BN_EPS);
        sc[t] = s;
        sh[t] = (b[t] - m[t]) * s + be[t];
    }
}

// ---------------- weight pack: W fp32 [K x 160] -> bf16 MFMA B-fragment order ----------------

template <int K>
__global__ __launch_bounds__(256) void pack_w_kernel(const float* __restrict__ W,
                                                     unsigned short* __restrict__ out) {
    int tid = blockIdx.x * 256 + threadIdx.x;
    if (tid >= K * 160) return;
    int j = tid & 7;
    int l = (tid >> 3) & 63;
    int u = (tid >> 9) % 10;
    int t = tid / 5120;
    int k = t * 32 + (l >> 4) * 8 + j;
    int nn = u * 16 + (l & 15);
    out[tid] = f2bf(W[k * 160 + nn]);
}

// ---------------- pre-scale + pack: out_bf16 = x * inv[node]  (C=128) ----------------

__global__ __launch_bounds__(256) void scale_bf16_kernel(const float* __restrict__ x,
                                                         const float* __restrict__ inv,
                                                         unsigned short* __restrict__ out,
                                                         int n) {
    int i = blockIdx.x * 256 + threadIdx.x;      // float4 index over n*32
    if (i < n * 32) {
        int node = i >> 5;
        float w = inv[node];
        float4 v = ((const float4*)x)[i];
        ushort4 o;
        o.x = f2bf(v.x * w); o.y = f2bf(v.y * w);
        o.z = f2bf(v.z * w); o.w = f2bf(v.w * w);
        ((ushort4*)out)[i] = o;
    }
}

// ---------------- grouped-gather aggregation (bf16 in, bf16 out) ----------------
// in_s[bf16] = h*inv (per-row). out[i] = bf16( inv[i] * (sum_nbr in_s[s] + in_s[i]) )
// Wave per node; wave split into G groups of LPR lanes; each group gathers a
// different edge's row with uint4 (16B) loads. C=160: G=3x20; C=128: G=4x16.

template <int C>
__global__ __launch_bounds__(256) void agg_grp_kernel(const unsigned short* __restrict__ in_s,
                                                      const float* __restrict__ inv,
                                                      const int* __restrict__ row_off,
                                                      const int* __restrict__ ssrc,
                                                      unsigned short* __restrict__ out, int n) {
    constexpr int LPR = C / 8;          // lanes per row (uint4 = 8 ch)
    constexpr int G   = 64 / LPR;       // concurrent edges per wave
    constexpr int RB  = C * 2;          // row bytes
    int wave = threadIdx.x >> 6;
    int lane = threadIdx.x & 63;
    int node = blockIdx.x * 4 + wave;
    if (node >= n) return;
    int g  = lane / LPR;
    int cl = lane - g * LPR;
    bool act = g < G;
    int beg = row_off[node], end = row_off[node + 1];
    const char* base = (const char*)in_s;
    int lb = cl * 16;

    float acc[8];
    #pragma unroll
    for (int i = 0; i < 8; ++i) acc[i] = 0.f;

    if (g == 0) {   // self-loop term
        uint4 r = *(const uint4*)(base + (size_t)node * RB + lb);
        addpk(acc, r);
    }

    int e = act ? beg + g : end;
    for (; e + G < end; e += 2 * G) {
        int s0 = ssrc[e], s1 = ssrc[e + G];
        uint4 r0 = *(const uint4*)(base + (size_t)s0 * RB + lb);
        uint4 r1 = *(const uint4*)(base + (size_t)s1 * RB + lb);
        addpk(acc, r0);
        addpk(acc, r1);
    }
    if (e < end) {
        uint4 r = *(const uint4*)(base + (size_t)ssrc[e] * RB + lb);
        addpk(acc, r);
    }

    // cross-group combine
    if (G == 4) {
        #pragma unroll
        for (int i = 0; i < 8; ++i) acc[i] += __shfl(acc[i], lane + 32);
        #pragma unroll
        for (int i = 0; i < 8; ++i) acc[i] += __shfl(acc[i], lane + 16);
    } else {
        #pragma unroll
        for (int i = 0; i < 8; ++i) {
            float a = __shfl(acc[i], lane + 20);
            float b = __shfl(acc[i], lane + 40);
            acc[i] += a + b;
        }
    }

    if (lane < LPR) {
        float wi = inv[node];
        uint4 o;
        o.x = pack2(acc[0] * wi, acc[1] * wi);
        o.y = pack2(acc[2] * wi, acc[3] * wi);
        o.z = pack2(acc[4] * wi, acc[5] * wi);
        o.w = pack2(acc[6] * wi, acc[7] * wi);
        *(uint4*)((char*)out + (size_t)node * RB + lb) = o;
    }
}

// ---------------- MFMA GEMM: relu((A[n x K]bf16 @ B[K x 160]bf16) * sc + sh) ----------------

template <int K, int OUTMODE>
__global__ __launch_bounds__(256) void mfma_gemm_kernel(const unsigned short* __restrict__ A,
                                                        const unsigned short* __restrict__ Bp,
                                                        const float* __restrict__ sc,
                                                        const float* __restrict__ sh,
                                                        const float* __restrict__ inv,
                                                        float* __restrict__ CoutF,
                                                        unsigned short* __restrict__ CoutB,
                                                        int n) {
    constexpr int KT = K / 32;
    int tid = threadIdx.x;
    int wave = tid >> 6, lane = tid & 63;
    int row0 = blockIdx.x * 64 + wave * 16;
    int m = lane & 15, q = lane >> 4;

    int arow = row0 + m;
    int arowc = (arow < n) ? arow : (n - 1);
    const frag8* Abase = (const frag8*)(A + (size_t)arowc * K);   // frag idx = t*4 + q
    const frag8* Bbase = (const frag8*)Bp;                        // frag idx = (t*10+u)*64 + lane

    facc4 acc[10];
    #pragma unroll
    for (int u = 0; u < 10; ++u) acc[u] = (facc4){0.f, 0.f, 0.f, 0.f};

    #pragma unroll
    for (int t = 0; t < KT; ++t) {
        frag8 af = Abase[t * 4 + q];
        #pragma unroll
        for (int u = 0; u < 10; ++u) {
            frag8 bf = Bbase[(t * 10 + u) * 64 + lane];
            acc[u] = __builtin_amdgcn_mfma_f32_16x16x32_bf16(af, bf, acc[u], 0, 0, 0);
        }
    }

    // D layout: col = lane&15 (within tile), row = q*4 + reg
    #pragma unroll
    for (int u = 0; u < 10; ++u) {
        int c = u * 16 + m;
        float scv = sc[c], shv = sh[c];
        #pragma unroll
        for (int r = 0; r < 4; ++r) {
            int rr = row0 + q * 4 + r;
            if (rr < n) {
                float v = fmaxf(acc[u][r] * scv + shv, 0.f);
                if (OUTMODE == 1) {
                    CoutB[(size_t)rr * 160 + c] = f2bf(v * inv[rr]);
                } else {
                    CoutF[(size_t)rr * 160 + c] = v;
                }
            }
        }
    }
}

// ---------------- mean pool (sorted batch) + MLP head ----------------

__global__ __launch_bounds__(256) void pool_head_kernel(const float* __restrict__ h,
                                                        const int* __restrict__ batch,
                                                        const float* __restrict__ Wc1,
                                                        const float* __restrict__ bc1,
                                                        const float* __restrict__ Wc2,
                                                        const float* __restrict__ bc2,
                                                        float* __restrict__ out, int n) {
    __shared__ float pooled[160];
    __shared__ float z[80];
    __shared__ int range[2];
    int g = blockIdx.x;
    int t = threadIdx.x;
    if (t < 2) {
        int target = g + t;
        int lo = 0, hi = n;
        while (lo < hi) {
            int mid = (lo + hi) >> 1;
            if (batch[mid] < target) lo = mid + 1; else hi = mid;
        }
        range[t] = lo;
    }
    __syncthreads();
    int lo = range[0], hi = range[1];
    if (t < 160) {
        float s = 0.f;
        for (int r = lo; r < hi; ++r) s += h[(size_t)r * 160 + t];
        pooled[t] = s / fmaxf((float)(hi - lo), 1.f);
    }
    __syncthreads();
    if (t < 80) {
        float s = bc1[t];
        for (int k = 0; k < 160; ++k) s += pooled[k] * Wc1[k * 80 + t];
        z[t] = fmaxf(s, 0.f);
    }
    __syncthreads();
    if (t < 2) {
        float s = bc2[t];
        for (int k = 0; k < 80; ++k) s += z[k] * Wc2[k * 2 + t];
        out[g * 2 + t] = s;
    }
}

// ---------------- launch ----------------

static inline size_t align256(size_t x) { return (x + 255) & ~(size_t)255; }

extern "C" void kernel_launch(void* const* d_in, const int* in_sizes, int n_in,
                              void* d_out, int out_size, void* d_ws, size_t ws_size,
                              hipStream_t stream) {
    const float* x   = (const float*)d_in[0];
    const int* ei    = (const int*)d_in[1];
    const int* batch = (const int*)d_in[2];
    const float* W1  = (const float*)d_in[3];
    const float* b1  = (const float*)d_in[4];
    const float* W2  = (const float*)d_in[5];
    const float* b2  = (const float*)d_in[6];
    const float* W3  = (const float*)d_in[7];
    const float* b3  = (const float*)d_in[8];
    const float* g1  = (const float*)d_in[9];
    const float* be1 = (const float*)d_in[10];
    const float* m1  = (const float*)d_in[11];
    const float* v1  = (const float*)d_in[12];
    const float* g2  = (const float*)d_in[13];
    const float* be2 = (const float*)d_in[14];
    const float* m2  = (const float*)d_in[15];
    const float* v2  = (const float*)d_in[16];
    const float* g3  = (const float*)d_in[17];
    const float* be3 = (const float*)d_in[18];
    const float* m3  = (const float*)d_in[19];
    const float* v3  = (const float*)d_in[20];
    const float* Wc1 = (const float*)d_in[21];
    const float* bc1 = (const float*)d_in[22];
    const float* Wc2 = (const float*)d_in[23];
    const float* bc2 = (const float*)d_in[24];
    float* out = (float*)d_out;

    const int N = in_sizes[2];          // 50000
    const int E = in_sizes[1] / 2;      // 1600000
    const int* src = ei;
    const int* dst = ei + E;

    char* w = (char*)d_ws;
    int*   row_off = (int*)w;             w += align256((size_t)(N + 1) * 4);
    float* inv     = (float*)w;           w += align256((size_t)N * 4);
    int*   ssrc    = (int*)w;             w += align256((size_t)E * 4);
    unsigned int* pairs = (unsigned int*)w; w += align256((size_t)E * 4);
    int*   cg      = (int*)w;             w += align256((size_t)NBKT_MAX * 4);
    int*   bucket_base   = (int*)w;       w += align256((size_t)(NBKT_MAX + 1) * 4);
    int*   bucket_cursor = (int*)w;       w += align256((size_t)NBKT_MAX * 4);
    float* scsh    = (float*)w;           w += align256((size_t)6 * HDIM * 4);
    unsigned short* W1p = (unsigned short*)w;  w += align256((size_t)FDIM_IN * HDIM * 2);
    unsigned short* W2p = (unsigned short*)w;  w += align256((size_t)HDIM * HDIM * 2);
    unsigned short* W3p = (unsigned short*)w;  w += align256((size_t)HDIM * HDIM * 2);
    unsigned short* bufA_bf = (unsigned short*)w;  w += align256((size_t)N * HDIM * 2);
    char* regionR = w;                    // reused region
    unsigned short* xs_bf = (unsigned short*)regionR;                           // N*128*2
    unsigned short* hs_bf = (unsigned short*)(regionR + align256((size_t)N * FDIM_IN * 2)); // N*160*2
    float* bufB = (float*)regionR;        // final h3 fp32 (aliases xs/hs, both dead by then)
    float* sc1 = scsh, *sh1 = scsh + 160, *sc2 = scsh + 320, *sh2 = scsh + 480,
         * sc3 = scsh + 640, *sh3 = scsh + 800;

    hipMemsetAsync(cg, 0, (size_t)NBKT_MAX * 4, stream);

    // two-level counting sort by dst -> row_off, ssrc, inv
    coarse_hist_kernel<<<256, 256, 0, stream>>>(dst, cg, E);
    coarse_scan_kernel<<<1, 128, 0, stream>>>(cg, bucket_base, bucket_cursor);
    part_kernel<<<256, 256, 0, stream>>>(src, dst, bucket_cursor, pairs, E);
    int nbkt = (N + 511) >> 9;
    bucket_csr_kernel<<<nbkt, 1024, 0, stream>>>(pairs, bucket_base, row_off, inv, ssrc, N);

    prep_kernel<<<1, 256, 0, stream>>>(b1, g1, be1, m1, v1, sc1, sh1);
    prep_kernel<<<1, 256, 0, stream>>>(b2, g2, be2, m2, v2, sc2, sh2);
    prep_kernel<<<1, 256, 0, stream>>>(b3, g3, be3, m3, v3, sc3, sh3);
    pack_w_kernel<128><<<(128 * 160 + 255) / 256, 256, 0, stream>>>(W1, W1p);
    pack_w_kernel<160><<<(160 * 160 + 255) / 256, 256, 0, stream>>>(W2, W2p);
    pack_w_kernel<160><<<(160 * 160 + 255) / 256, 256, 0, stream>>>(W3, W3p);

    int gAgg = (N + 3) / 4;
    int gGemm = (N + 63) / 64;

    // layer 1: xs = bf16(x*inv); agg; MFMA GEMM(K=128)+BN+ReLU -> bf16(h*inv)
    scale_bf16_kernel<<<(N * 32 + 255) / 256, 256, 0, stream>>>(x, inv, xs_bf, N);
    agg_grp_kernel<128><<<gAgg, 256, 0, stream>>>(xs_bf, inv, row_off, ssrc, bufA_bf, N);
    mfma_gemm_kernel<128, 1><<<gGemm, 256, 0, stream>>>(bufA_bf, W1p, sc1, sh1, inv, nullptr, hs_bf, N);
    // layer 2
    agg_grp_kernel<160><<<gAgg, 256, 0, stream>>>(hs_bf, inv, row_off, ssrc, bufA_bf, N);
    mfma_gemm_kernel<160, 1><<<gGemm, 256, 0, stream>>>(bufA_bf, W2p, sc2, sh2, inv, nullptr, hs_bf, N);
    // layer 3: fp32 unscaled h3 for pooling (bufB aliases dead xs/hs region)
    agg_grp_kernel<160><<<gAgg, 256, 0, stream>>>(hs_bf, inv, row_off, ssrc, bufA_bf, N);
    mfma_gemm_kernel<160, 0><<<gGemm, 256, 0, stream>>>(bufA_bf, W3p, sc3, sh3, inv, bufB, nullptr, N);

    pool_head_kernel<<<N_GRAPHS, 256, 0, stream>>>(bufB, batch, Wc1, bc1, Wc2, bc2, out, N);
}